// Round 11
// baseline (390.670 us; speedup 1.0000x reference)
//
#include <hip/hip_runtime.h>
#include <math.h>

#define NRES 512
#define HH 12
#define PQn 4
#define PVn 8
#define En 16
#define Cn 128
#define Sn 384
#define ATT_COLS 2112   // 192 att_single | 1536 att_pair | 288 points | 96 norms

// workspace float offsets
#define OFF_Q    0
#define OFF_K    (OFF_Q   + HH*NRES*En)
#define OFF_V    (OFF_K   + HH*NRES*En)
#define OFF_LQP  (OFF_V   + HH*NRES*En)
#define OFF_LKP  (OFF_LQP + HH*NRES*12)
#define OFF_LVP  (OFF_LKP + HH*NRES*12)
#define OFF_CS   (OFF_LVP + HH*NRES*24)     // colsum [b][h]  (transposed)
#define OFF_ATT  (OFF_CS  + NRES*HH)        // att [NRES][ATT_COLS]
#define OFF_LG   (OFF_ATT + NRES*ATT_COLS)  // logits/weights [H][N][N] (12.6 MB)
// out-GEMM partial buffer aliases LG (lg dead by then)
#define OFF_PART OFF_LG
// packed logit operands alias ATT (consumed by ipa_logits before att written)
#define OFF_KC   OFF_ATT                    // [N][H][28]  (0.25*k | 2g*lkp)
#define OFF_D1   (OFF_KC + NRES*HH*28)      // [N][H]  -g*|lkp|^2
#define OFF_D0   (OFF_D1 + NRES*HH)         // [N][H]  -g*|lqp|^2
#define OFF_QC   (OFF_D0 + NRES*HH)         // [N][H][28]  (q | lqp)
#define KSPLIT 16
#define KCHUNK (ATT_COLS/KSPLIT)   // 132
#define OROWS 8                    // rows per out-GEMM block

// ---------------------------------------------------------------------------
// Kernel A: projections q/k/v and point projections with frame application.
// ---------------------------------------------------------------------------
__global__ __launch_bounds__(256) void ipa_proj(
    const float* __restrict__ single, const float* __restrict__ Rm,
    const float* __restrict__ tr,
    const float* __restrict__ Wq, const float* __restrict__ Wk,
    const float* __restrict__ Wv, const float* __restrict__ Wqp,
    const float* __restrict__ Wkp, const float* __restrict__ Wvp,
    float* __restrict__ ws)
{
  float* q   = ws + OFF_Q;  float* k   = ws + OFF_K;  float* v   = ws + OFF_V;
  float* lqp = ws + OFF_LQP; float* lkp = ws + OFF_LKP; float* lvp = ws + OFF_LVP;
  const int n0 = blockIdx.x * 8;
  const int g  = blockIdx.y;
  const int tid = threadIdx.x;
  __shared__ float sS[8][388];
  __shared__ float sR[8][9];
  __shared__ float sT[8][3];
  #pragma unroll
  for (int i = 0; i < 3; ++i) {
    int idx = i*256 + tid;
    int r = idx / 96, c4 = idx % 96;
    float4 val = *reinterpret_cast<const float4*>(single + (size_t)(n0 + r)*Sn + c4*4);
    *reinterpret_cast<float4*>(&sS[r][c4*4]) = val;
  }
  if (tid < 72)      sR[tid/9][tid%9] = Rm[(size_t)(n0 + tid/9)*9 + tid%9];
  else if (tid < 96) { int r = (tid-72)/3; sT[r][(tid-72)%3] = tr[(size_t)(n0+r)*3 + (tid-72)%3]; }
  __syncthreads();
  #pragma unroll
  for (int i = 0; i < 3; ++i) {
    int item = i*256 + tid;
    int nl = item & 7;
    int ul = item >> 3;
    int u  = g*96 + ul;
    const float* srow = sS[nl];
    if (u < 576) {
      int which = u/192, r = u%192, h = r>>4, e = r&15;
      const float* W = (which==0 ? Wq : which==1 ? Wk : Wv) + (size_t)h*Sn*En + e;
      float acc = 0.f;
      #pragma unroll 8
      for (int d = 0; d < Sn; ++d) acc = fmaf(srow[d], W[(size_t)d*En], acc);
      float* dst = (which==0 ? q : which==1 ? k : v);
      dst[((size_t)h*NRES + (n0+nl))*En + e] = acc;
    } else {
      int u2 = u - 576;
      const float* W; float* dst;
      if (u2 < 48)      { int h=u2>>2,     p=u2&3;      W = Wqp + (size_t)(h*PQn+p)*Sn*3; dst = lqp + ((size_t)h*NRES + (n0+nl))*12 + p*3; }
      else if (u2 < 96) { int h=(u2-48)>>2,p=(u2-48)&3; W = Wkp + (size_t)(h*PQn+p)*Sn*3; dst = lkp + ((size_t)h*NRES + (n0+nl))*12 + p*3; }
      else              { int h=(u2-96)>>3,p=(u2-96)&7; W = Wvp + (size_t)(h*PVn+p)*Sn*3; dst = lvp + ((size_t)h*NRES + (n0+nl))*24 + p*3; }
      float x0=0.f,x1=0.f,x2=0.f;
      #pragma unroll 4
      for (int d = 0; d < Sn; ++d) {
        float sv = srow[d];
        x0 = fmaf(sv, W[d*3+0], x0);
        x1 = fmaf(sv, W[d*3+1], x1);
        x2 = fmaf(sv, W[d*3+2], x2);
      }
      const float* R8 = sR[nl]; const float* T8 = sT[nl];
      dst[0] = R8[0]*x0 + R8[1]*x1 + R8[2]*x2 + T8[0];
      dst[1] = R8[3]*x0 + R8[4]*x1 + R8[5]*x2 + T8[1];
      dst[2] = R8[6]*x0 + R8[7]*x1 + R8[8]*x2 + T8[2];
    }
  }
}

// ---------------------------------------------------------------------------
// Kernel A2: pack per-(m,h) logit operands.
// ---------------------------------------------------------------------------
__global__ __launch_bounds__(256) void ipa_pack(
    const float* __restrict__ scale_head, float* __restrict__ ws)
{
  const float* q   = ws + OFF_Q;
  const float* k   = ws + OFF_K;
  const float* lkp = ws + OFF_LKP;
  const float* lqp = ws + OFF_LQP;
  float* kc = ws + OFF_KC;
  float* qc = ws + OFF_QC;
  float* d1 = ws + OFF_D1;
  float* d0 = ws + OFF_D0;
  const int idx = blockIdx.x*256 + threadIdx.x;   // 0..6143
  const int h = idx >> 9, m = idx & 511;
  const float gamma = 0.11785113019775793f * log1pf(__expf(scale_head[h]));
  const float* kr  = k   + ((size_t)h*NRES + m)*En;
  const float* qr  = q   + ((size_t)h*NRES + m)*En;
  const float* lkr = lkp + ((size_t)h*NRES + m)*12;
  const float* lqr = lqp + ((size_t)h*NRES + m)*12;
  float* kcr = kc + ((size_t)m*HH + h)*28;
  float* qcr = qc + ((size_t)m*HH + h)*28;
  #pragma unroll
  for (int e = 0; e < En; ++e) { kcr[e] = 0.25f * kr[e]; qcr[e] = qr[e]; }
  float Bm = 0.f, An = 0.f;
  #pragma unroll
  for (int j = 0; j < 12; ++j) {
    float b = lkr[j], a = lqr[j];
    kcr[16+j] = (2.f*gamma)*b;
    qcr[16+j] = a;
    Bm = fmaf(b, b, Bm);
    An = fmaf(a, a, An);
  }
  d1[m*HH + h] = -gamma*Bm;
  d0[m*HH + h] = -gamma*An;
}

// ---------------------------------------------------------------------------
// Kernel B: logits[h][n][m]. Line-perfect streaming + LDS-staged writes.
// Wave = 16 row-clusters x 4 lanes (r, cq). Lane reads channel quarter cq of
// rows m and m+64: 4-lane cluster consumes full contiguous 64B lines (no NT:
// L3 keeps absorbing pair re-reads). Wb in LDS. Butterfly + static select.
// Results staged in padded LDS, then written as full-line coalesced float4
// runs (fixes R10's 14x write amplification). grid (512 n, 4 mt), 256 thr.
// ---------------------------------------------------------------------------
__global__ __launch_bounds__(256, 4) void ipa_logits(
    const float* __restrict__ pair, const float* __restrict__ Wb,
    float* __restrict__ ws)
{
  const float* kc = ws + OFF_KC;
  const float* qc = ws + OFF_QC;
  const float* d1 = ws + OFF_D1;
  const float* d0 = ws + OFF_D0;
  float* lg = ws + OFF_LG;

  __shared__ float sWb[HH*Cn];      // 6 KB
  __shared__ float sOut[HH*132];    // 6.2 KB, pad 132 -> conflict-free
  for (int i = threadIdx.x; i < HH*Cn/4; i += 256)
    reinterpret_cast<float4*>(sWb)[i] = reinterpret_cast<const float4*>(Wb)[i];
  __syncthreads();

  const int n    = blockIdx.x;
  const int tid  = threadIdx.x;
  const int lane = tid & 63;
  const int wave = tid >> 6;
  const int r    = lane >> 2;     // 0..15
  const int cq   = lane & 3;      // 0..3
  const int ml   = wave*16 + r;   // 0..63 local m
  const int m    = blockIdx.y*128 + ml;
  const int m2   = m + 64;

  // burst: both rows' channel quarters (64B-line clusters per 4 lanes)
  const float* p1 = pair + ((size_t)n*NRES + m )*Cn + cq*4;
  const float* p2 = pair + ((size_t)n*NRES + m2)*Cn + cq*4;
  float4 pv[8], pw[8];
  #pragma unroll
  for (int jg = 0; jg < 8; ++jg) {
    pv[jg] = *reinterpret_cast<const float4*>(p1 + jg*16);
    pw[jg] = *reinterpret_cast<const float4*>(p2 + jg*16);
  }

  float acc1[HH], acc2[HH];
  #pragma unroll
  for (int h = 0; h < HH; ++h) { acc1[h] = 0.f; acc2[h] = 0.f; }
  #pragma unroll
  for (int jg = 0; jg < 8; ++jg) {
    #pragma unroll
    for (int h = 0; h < HH; ++h) {
      const float4 wb = *reinterpret_cast<const float4*>(&sWb[h*Cn + jg*16 + cq*4]);
      acc1[h] += pv[jg].x*wb.x + pv[jg].y*wb.y + pv[jg].z*wb.z + pv[jg].w*wb.w;
      acc2[h] += pw[jg].x*wb.x + pw[jg].y*wb.y + pw[jg].z*wb.z + pw[jg].w*wb.w;
    }
  }
  // butterfly over the 4 cq lanes: every lane gets full 128-ch sums
  #pragma unroll
  for (int h = 0; h < HH; ++h) {
    acc1[h] += __shfl_xor(acc1[h], 1);
    acc1[h] += __shfl_xor(acc1[h], 2);
    acc2[h] += __shfl_xor(acc2[h], 1);
    acc2[h] += __shfl_xor(acc2[h], 2);
  }
  // static 4-way select of this lane's 3 heads (no runtime-indexed regs)
  float b10, b11, b12, b20, b21, b22;
  if      (cq == 0) { b10=acc1[0]; b11=acc1[1];  b12=acc1[2];
                      b20=acc2[0]; b21=acc2[1];  b22=acc2[2]; }
  else if (cq == 1) { b10=acc1[3]; b11=acc1[4];  b12=acc1[5];
                      b20=acc2[3]; b21=acc2[4];  b22=acc2[5]; }
  else if (cq == 2) { b10=acc1[6]; b11=acc1[7];  b12=acc1[8];
                      b20=acc2[6]; b21=acc2[7];  b22=acc2[8]; }
  else              { b10=acc1[9]; b11=acc1[10]; b12=acc1[11];
                      b20=acc2[9]; b21=acc2[10]; b22=acc2[11]; }

  const int hb = 3*cq;
  const float* kc1 = kc + ((size_t)m *HH + hb)*28;
  const float* kc2 = kc + ((size_t)m2*HH + hb)*28;
  const float* qcn = qc + ((size_t)n *HH + hb)*28;
  const float* d0n = d0 + (size_t)n*HH + hb;
  const float* d11 = d1 + (size_t)m *HH + hb;
  const float* d12 = d1 + (size_t)m2*HH + hb;

  #pragma unroll
  for (int i = 0; i < 3; ++i) {
    float t1 = (i==0 ? b10 : i==1 ? b11 : b12) + d11[i] + d0n[i];
    float t2 = (i==0 ? b20 : i==1 ? b21 : b22) + d12[i] + d0n[i];
    #pragma unroll
    for (int j = 0; j < 7; ++j) {
      float4 qv = *reinterpret_cast<const float4*>(qcn + i*28 + j*4);
      float4 k1 = *reinterpret_cast<const float4*>(kc1 + i*28 + j*4);
      float4 k2 = *reinterpret_cast<const float4*>(kc2 + i*28 + j*4);
      t1 += k1.x*qv.x + k1.y*qv.y + k1.z*qv.z + k1.w*qv.w;
      t2 += k2.x*qv.x + k2.y*qv.y + k2.z*qv.z + k2.w*qv.w;
    }
    sOut[(hb+i)*132 + ml]      = t1;
    sOut[(hb+i)*132 + ml + 64] = t2;
  }
  __syncthreads();
  // coalesced full-line writes: 12 heads x 128 floats = 384 float4
  for (int idx = tid; idx < HH*32; idx += 256) {
    const int h = idx >> 5, q4 = idx & 31;
    float4 o = make_float4(sOut[h*132 + q4*4 + 0], sOut[h*132 + q4*4 + 1],
                           sOut[h*132 + q4*4 + 2], sOut[h*132 + q4*4 + 3]);
    *reinterpret_cast<float4*>(
        lg + ((size_t)h*NRES + n)*NRES + blockIdx.y*128 + q4*4) = o;
  }
}

// ---------------------------------------------------------------------------
// Kernel C: softmax in place over last axis of lg[H][N][N]. One wave per row.
// ---------------------------------------------------------------------------
__global__ __launch_bounds__(256) void ipa_softmax(float* __restrict__ ws)
{
  float* lg = ws + OFF_LG;
  const int row  = blockIdx.x*4 + (threadIdx.x >> 6);
  const int lane = threadIdx.x & 63;
  float4* p = reinterpret_cast<float4*>(lg + (size_t)row*NRES);
  float4 x0 = p[lane];
  float4 x1 = p[64 + lane];
  float mx = fmaxf(fmaxf(fmaxf(x0.x,x0.y),fmaxf(x0.z,x0.w)),
                   fmaxf(fmaxf(x1.x,x1.y),fmaxf(x1.z,x1.w)));
  #pragma unroll
  for (int off = 32; off >= 1; off >>= 1) mx = fmaxf(mx, __shfl_xor(mx, off));
  x0.x = __expf(x0.x-mx); x0.y = __expf(x0.y-mx); x0.z = __expf(x0.z-mx); x0.w = __expf(x0.w-mx);
  x1.x = __expf(x1.x-mx); x1.y = __expf(x1.y-mx); x1.z = __expf(x1.z-mx); x1.w = __expf(x1.w-mx);
  float sum = x0.x+x0.y+x0.z+x0.w + x1.x+x1.y+x1.z+x1.w;
  #pragma unroll
  for (int off = 32; off >= 1; off >>= 1) sum += __shfl_xor(sum, off);
  const float inv = 1.f/sum;
  x0.x*=inv; x0.y*=inv; x0.z*=inv; x0.w*=inv;
  x1.x*=inv; x1.y*=inv; x1.z*=inv; x1.w*=inv;
  p[lane] = x0;
  p[64 + lane] = x1;
}

// ---------------------------------------------------------------------------
// Kernel D: colsum[b][h] = sum_a w[h][a][b] (transposed). grid (12, 16).
// ---------------------------------------------------------------------------
__global__ __launch_bounds__(256) void ipa_colsum(float* __restrict__ ws)
{
  const float* lg = ws + OFF_LG;
  float* cs = ws + OFF_CS;
  const int h = blockIdx.x, ac = blockIdx.y, tid = threadIdx.x;
  const float* base = lg + (size_t)h*NRES*NRES + (size_t)ac*32*NRES;
  float acc0 = 0.f, acc1 = 0.f;
  #pragma unroll 4
  for (int a = 0; a < 32; ++a) {
    acc0 += base[(size_t)a*NRES + tid];
    acc1 += base[(size_t)a*NRES + tid + 256];
  }
  atomicAdd(&cs[(size_t)tid*HH + h],       acc0);
  atomicAdd(&cs[(size_t)(tid+256)*HH + h], acc1);
}

// ---------------------------------------------------------------------------
// Kernel E: att_single = w.v, local_out = w.lvp, inverse frame + norms.
// ---------------------------------------------------------------------------
__global__ __launch_bounds__(256) void ipa_agg(
    const float* __restrict__ Rm, const float* __restrict__ tr,
    float* __restrict__ ws)
{
  const float* v   = ws + OFF_V;
  const float* lvp = ws + OFF_LVP;
  const float* lg  = ws + OFF_LG;
  float* att = ws + OFF_ATT;
  const int row  = blockIdx.x*4 + (threadIdx.x >> 6);
  const int lane = threadIdx.x & 63;
  const int h = row >> 9, n = row & 511;

  float acc[40];
  #pragma unroll
  for (int i = 0; i < 40; ++i) acc[i] = 0.f;

  const float* wrow = lg + (size_t)row*NRES;
  #pragma unroll 2
  for (int j = 0; j < 8; ++j) {
    const int m = j*64 + lane;
    const float wv = wrow[m];
    const float4* v4 = reinterpret_cast<const float4*>(v + ((size_t)h*NRES + m)*En);
    float4 a0=v4[0], a1=v4[1], a2=v4[2], a3=v4[3];
    acc[0]+=wv*a0.x; acc[1]+=wv*a0.y; acc[2]+=wv*a0.z; acc[3]+=wv*a0.w;
    acc[4]+=wv*a1.x; acc[5]+=wv*a1.y; acc[6]+=wv*a1.z; acc[7]+=wv*a1.w;
    acc[8]+=wv*a2.x; acc[9]+=wv*a2.y; acc[10]+=wv*a2.z; acc[11]+=wv*a2.w;
    acc[12]+=wv*a3.x; acc[13]+=wv*a3.y; acc[14]+=wv*a3.z; acc[15]+=wv*a3.w;
    const float4* l4 = reinterpret_cast<const float4*>(lvp + ((size_t)h*NRES + m)*24);
    #pragma unroll
    for (int t = 0; t < 6; ++t) {
      float4 b = l4[t];
      acc[16+4*t+0]+=wv*b.x; acc[16+4*t+1]+=wv*b.y;
      acc[16+4*t+2]+=wv*b.z; acc[16+4*t+3]+=wv*b.w;
    }
  }
  #pragma unroll
  for (int off = 32; off >= 1; off >>= 1) {
    #pragma unroll
    for (int i = 0; i < 40; ++i) acc[i] += __shfl_xor(acc[i], off);
  }
  if (lane == 0) {
    size_t ab = (size_t)n*ATT_COLS;
    float4* as = reinterpret_cast<float4*>(att + ab + h*En);
    as[0] = make_float4(acc[0],acc[1],acc[2],acc[3]);
    as[1] = make_float4(acc[4],acc[5],acc[6],acc[7]);
    as[2] = make_float4(acc[8],acc[9],acc[10],acc[11]);
    as[3] = make_float4(acc[12],acc[13],acc[14],acc[15]);
    const float R0=Rm[n*9+0],R1=Rm[n*9+1],R2=Rm[n*9+2],
                R3=Rm[n*9+3],R4=Rm[n*9+4],R5=Rm[n*9+5],
                R6=Rm[n*9+6],R7=Rm[n*9+7],R8=Rm[n*9+8];
    const float t0=tr[n*3+0], t1=tr[n*3+1], t2=tr[n*3+2];
    #pragma unroll
    for (int pp = 0; pp < 8; ++pp) {
      float d0 = acc[16+3*pp+0]-t0, d1 = acc[16+3*pp+1]-t1, d2 = acc[16+3*pp+2]-t2;
      float g0 = R0*d0 + R3*d1 + R6*d2;
      float g1 = R1*d0 + R4*d1 + R7*d2;
      float g2 = R2*d0 + R5*d1 + R8*d2;
      att[ab + 1728 + (pp*HH + h)*3 + 0] = g0;
      att[ab + 1728 + (pp*HH + h)*3 + 1] = g1;
      att[ab + 1728 + (pp*HH + h)*3 + 2] = g2;
      att[ab + 2016 + pp*HH + h] = sqrtf(g0*g0 + g1*g1 + g2*g2);
    }
  }
}

// ---------------------------------------------------------------------------
// Kernel F: att_pair[h,i,c] = sum_b cs[b][h]*pair[i,b,c]. One block per i.
// 512 threads (16 b-groups x 32 c4), 72 KB LDS -> 2 blocks/CU.
// ---------------------------------------------------------------------------
__global__ __launch_bounds__(512) void ipa_pairagg(
    const float* __restrict__ pair, float* __restrict__ ws)
{
  const float* cs = ws + OFF_CS;       // [b][h]
  float* att = ws + OFF_ATT;
  const int i = blockIdx.x, tid = threadIdx.x;
  __shared__ float sCS[NRES*HH];       // 24 KB
  __shared__ float4 sRed[8][HH][32];   // 48 KB
  for (int idx = tid; idx < NRES*HH/4; idx += 512)
    reinterpret_cast<float4*>(sCS)[idx] = reinterpret_cast<const float4*>(cs)[idx];
  __syncthreads();
  const int c4 = tid & 31, bg = tid >> 5;   // bg 0..15
  const int b0 = bg * 32;
  float4 acc[HH];
  #pragma unroll
  for (int h = 0; h < HH; ++h) acc[h] = make_float4(0.f,0.f,0.f,0.f);
  const float* prow = pair + (size_t)i*NRES*Cn;
  for (int jb = 0; jb < 32; jb += 4) {
    float4 pv[4];
    #pragma unroll
    for (int u = 0; u < 4; ++u)
      pv[u] = *reinterpret_cast<const float4*>(prow + (size_t)(b0+jb+u)*Cn + c4*4);
    #pragma unroll
    for (int u = 0; u < 4; ++u) {
      const float4* csr = reinterpret_cast<const float4*>(&sCS[(b0+jb+u)*HH]);
      float4 c0 = csr[0], c1 = csr[1], c2 = csr[2];
      float w[12] = {c0.x,c0.y,c0.z,c0.w, c1.x,c1.y,c1.z,c1.w, c2.x,c2.y,c2.z,c2.w};
      #pragma unroll
      for (int h = 0; h < HH; ++h) {
        acc[h].x = fmaf(w[h], pv[u].x, acc[h].x);
        acc[h].y = fmaf(w[h], pv[u].y, acc[h].y);
        acc[h].z = fmaf(w[h], pv[u].z, acc[h].z);
        acc[h].w = fmaf(w[h], pv[u].w, acc[h].w);
      }
    }
  }
  // 16 -> 8
  if (bg >= 8) {
    for (int h = 0; h < HH; ++h) sRed[bg-8][h][c4] = acc[h];
  }
  __syncthreads();
  if (bg < 8) {
    for (int h = 0; h < HH; ++h) {
      float4 b2 = sRed[bg][h][c4];
      acc[h].x+=b2.x; acc[h].y+=b2.y; acc[h].z+=b2.z; acc[h].w+=b2.w;
    }
  }
  __syncthreads();
  // 8 -> 4
  if (bg >= 4 && bg < 8) {
    for (int h = 0; h < HH; ++h) sRed[bg-4][h][c4] = acc[h];
  }
  __syncthreads();
  if (bg < 4) {
    for (int h = 0; h < HH; ++h) {
      float4 b2 = sRed[bg][h][c4];
      acc[h].x+=b2.x; acc[h].y+=b2.y; acc[h].z+=b2.z; acc[h].w+=b2.w;
    }
  }
  __syncthreads();
  // 4 -> 2
  if (bg >= 2 && bg < 4) {
    for (int h = 0; h < HH; ++h) sRed[bg-2][h][c4] = acc[h];
  }
  __syncthreads();
  if (bg < 2) {
    for (int h = 0; h < HH; ++h) {
      float4 b2 = sRed[bg][h][c4];
      acc[h].x+=b2.x; acc[h].y+=b2.y; acc[h].z+=b2.z; acc[h].w+=b2.w;
    }
  }
  __syncthreads();
  // 2 -> 1 + write
  if (bg == 1) {
    for (int h = 0; h < HH; ++h) sRed[0][h][c4] = acc[h];
  }
  __syncthreads();
  if (bg == 0) {
    size_t base = (size_t)i*ATT_COLS + 192;
    for (int h = 0; h < HH; ++h) {
      float4 b2 = sRed[0][h][c4];
      acc[h].x+=b2.x; acc[h].y+=b2.y; acc[h].z+=b2.z; acc[h].w+=b2.w;
      *reinterpret_cast<float4*>(att + base + h*Cn + c4*4) = acc[h];
    }
  }
}

// ---------------------------------------------------------------------------
// Kernel G1: split-k partial GEMM. grid (64 rowblocks, 16 ksplits), 384 thr.
// ---------------------------------------------------------------------------
__global__ __launch_bounds__(384) void ipa_outp(
    const float* __restrict__ att, const float* __restrict__ Wout,
    float* __restrict__ ws)
{
  float* partial = ws + OFF_PART;       // [KSPLIT][NRES][Sn]
  const int rb = blockIdx.x;
  const int ks = blockIdx.y;
  const int s  = threadIdx.x;
  const int n0 = rb*OROWS;
  const int j0 = ks*KCHUNK;

  float acc[OROWS];
  #pragma unroll
  for (int r = 0; r < OROWS; ++r) acc[r] = 0.f;

  for (int jg = 0; jg < KCHUNK/4; ++jg) {
    const int j = j0 + jg*4;
    float w0 = Wout[(size_t)(j+0)*Sn + s];
    float w1 = Wout[(size_t)(j+1)*Sn + s];
    float w2 = Wout[(size_t)(j+2)*Sn + s];
    float w3 = Wout[(size_t)(j+3)*Sn + s];
    #pragma unroll
    for (int r = 0; r < OROWS; ++r) {
      float4 av = *reinterpret_cast<const float4*>(att + (size_t)(n0+r)*ATT_COLS + j);
      acc[r] = fmaf(av.x, w0, acc[r]);
      acc[r] = fmaf(av.y, w1, acc[r]);
      acc[r] = fmaf(av.z, w2, acc[r]);
      acc[r] = fmaf(av.w, w3, acc[r]);
    }
  }
  #pragma unroll
  for (int r = 0; r < OROWS; ++r)
    partial[((size_t)ks*NRES + n0 + r)*Sn + s] = acc[r];
}

// ---------------------------------------------------------------------------
// Kernel G2: out[n][s] = b_out[s] + sum_ks partial[ks][n][s].
// ---------------------------------------------------------------------------
__global__ __launch_bounds__(384) void ipa_outred(
    const float* __restrict__ b_out, float* __restrict__ ws,
    float* __restrict__ out)
{
  const float* partial = ws + OFF_PART;
  const int n = blockIdx.x, s = threadIdx.x;
  float a = b_out[s];
  #pragma unroll
  for (int ks = 0; ks < KSPLIT; ++ks)
    a += partial[((size_t)ks*NRES + n)*Sn + s];
  out[(size_t)n*Sn + s] = a;
}

// ---------------------------------------------------------------------------
extern "C" void kernel_launch(void* const* d_in, const int* in_sizes, int n_in,
                              void* d_out, int out_size, void* d_ws, size_t ws_size,
                              hipStream_t stream) {
  const float* single = (const float*)d_in[0];
  const float* pair   = (const float*)d_in[1];
  const float* Rm     = (const float*)d_in[2];
  const float* tr     = (const float*)d_in[3];
  const float* Wq     = (const float*)d_in[4];
  const float* Wk     = (const float*)d_in[5];
  const float* Wv     = (const float*)d_in[6];
  const float* Wqp    = (const float*)d_in[7];
  const float* Wkp    = (const float*)d_in[8];
  const float* Wvp    = (const float*)d_in[9];
  const float* Wb     = (const float*)d_in[10];
  const float* Wout   = (const float*)d_in[11];
  const float* b_out  = (const float*)d_in[12];
  const float* scale_head = (const float*)d_in[13];
  float* ws  = (float*)d_ws;
  float* out = (float*)d_out;

  hipMemsetAsync(ws + OFF_CS, 0, NRES*HH*sizeof(float), stream);
  ipa_proj   <<<dim3(64, 8),  256, 0, stream>>>(single, Rm, tr, Wq, Wk, Wv, Wqp, Wkp, Wvp, ws);
  ipa_pack   <<<dim3(24),     256, 0, stream>>>(scale_head, ws);
  ipa_logits <<<dim3(NRES, 4), 256, 0, stream>>>(pair, Wb, ws);
  ipa_softmax<<<dim3(HH*NRES/4), 256, 0, stream>>>(ws);
  ipa_colsum <<<dim3(HH, 16), 256, 0, stream>>>(ws);
  ipa_agg    <<<dim3(HH*NRES/4), 256, 0, stream>>>(Rm, tr, ws);
  ipa_pairagg<<<dim3(NRES),   512, 0, stream>>>(pair, ws);
  ipa_outp   <<<dim3(NRES/OROWS, KSPLIT), 384, 0, stream>>>(ws + OFF_ATT, Wout, ws);
  ipa_outred <<<dim3(NRES),   384, 0, stream>>>(b_out, ws, out);
}

// Round 12
// 270.576 us; speedup vs baseline: 1.4438x; 1.4438x over previous
//
#include <hip/hip_runtime.h>
#include <math.h>

#define NRES 512
#define HH 12
#define PQn 4
#define PVn 8
#define En 16
#define Cn 128
#define Sn 384
#define ATT_COLS 2112   // 192 att_single | 1536 att_pair | 288 points | 96 norms

// workspace float offsets
#define OFF_Q    0
#define OFF_K    (OFF_Q   + HH*NRES*En)
#define OFF_V    (OFF_K   + HH*NRES*En)
#define OFF_LQP  (OFF_V   + HH*NRES*En)
#define OFF_LKP  (OFF_LQP + HH*NRES*12)
#define OFF_LVP  (OFF_LKP + HH*NRES*12)
#define OFF_CS   (OFF_LVP + HH*NRES*24)     // colsum [b][h]  (transposed)
#define OFF_ATT  (OFF_CS  + NRES*HH)        // att [NRES][ATT_COLS]
#define OFF_LG   (OFF_ATT + NRES*ATT_COLS)  // logits/weights [H][N][N] (12.6 MB)
// out-GEMM partial buffer aliases LG (lg dead by then)
#define OFF_PART OFF_LG
// packed logit operands alias ATT (consumed by ipa_logits before att written)
#define OFF_KC   OFF_ATT                    // [N][H][28]  (0.25*k | 2g*lkp)
#define OFF_D1   (OFF_KC + NRES*HH*28)      // [N][H]  -g*|lkp|^2
#define OFF_D0   (OFF_D1 + NRES*HH)         // [N][H]  -g*|lqp|^2
#define OFF_QC   (OFF_D0 + NRES*HH)         // [N][H][28]  (q | lqp)
#define KSPLIT 16
#define KCHUNK (ATT_COLS/KSPLIT)   // 132
#define OROWS 8                    // rows per out-GEMM block

// ---------------------------------------------------------------------------
// Kernel A: projections q/k/v and point projections with frame application.
// ---------------------------------------------------------------------------
__global__ __launch_bounds__(256) void ipa_proj(
    const float* __restrict__ single, const float* __restrict__ Rm,
    const float* __restrict__ tr,
    const float* __restrict__ Wq, const float* __restrict__ Wk,
    const float* __restrict__ Wv, const float* __restrict__ Wqp,
    const float* __restrict__ Wkp, const float* __restrict__ Wvp,
    float* __restrict__ ws)
{
  float* q   = ws + OFF_Q;  float* k   = ws + OFF_K;  float* v   = ws + OFF_V;
  float* lqp = ws + OFF_LQP; float* lkp = ws + OFF_LKP; float* lvp = ws + OFF_LVP;
  const int n0 = blockIdx.x * 8;
  const int g  = blockIdx.y;
  const int tid = threadIdx.x;
  __shared__ float sS[8][388];
  __shared__ float sR[8][9];
  __shared__ float sT[8][3];
  #pragma unroll
  for (int i = 0; i < 3; ++i) {
    int idx = i*256 + tid;
    int r = idx / 96, c4 = idx % 96;
    float4 val = *reinterpret_cast<const float4*>(single + (size_t)(n0 + r)*Sn + c4*4);
    *reinterpret_cast<float4*>(&sS[r][c4*4]) = val;
  }
  if (tid < 72)      sR[tid/9][tid%9] = Rm[(size_t)(n0 + tid/9)*9 + tid%9];
  else if (tid < 96) { int r = (tid-72)/3; sT[r][(tid-72)%3] = tr[(size_t)(n0+r)*3 + (tid-72)%3]; }
  __syncthreads();
  #pragma unroll
  for (int i = 0; i < 3; ++i) {
    int item = i*256 + tid;
    int nl = item & 7;
    int ul = item >> 3;
    int u  = g*96 + ul;
    const float* srow = sS[nl];
    if (u < 576) {
      int which = u/192, r = u%192, h = r>>4, e = r&15;
      const float* W = (which==0 ? Wq : which==1 ? Wk : Wv) + (size_t)h*Sn*En + e;
      float acc = 0.f;
      #pragma unroll 8
      for (int d = 0; d < Sn; ++d) acc = fmaf(srow[d], W[(size_t)d*En], acc);
      float* dst = (which==0 ? q : which==1 ? k : v);
      dst[((size_t)h*NRES + (n0+nl))*En + e] = acc;
    } else {
      int u2 = u - 576;
      const float* W; float* dst;
      if (u2 < 48)      { int h=u2>>2,     p=u2&3;      W = Wqp + (size_t)(h*PQn+p)*Sn*3; dst = lqp + ((size_t)h*NRES + (n0+nl))*12 + p*3; }
      else if (u2 < 96) { int h=(u2-48)>>2,p=(u2-48)&3; W = Wkp + (size_t)(h*PQn+p)*Sn*3; dst = lkp + ((size_t)h*NRES + (n0+nl))*12 + p*3; }
      else              { int h=(u2-96)>>3,p=(u2-96)&7; W = Wvp + (size_t)(h*PVn+p)*Sn*3; dst = lvp + ((size_t)h*NRES + (n0+nl))*24 + p*3; }
      float x0=0.f,x1=0.f,x2=0.f;
      #pragma unroll 4
      for (int d = 0; d < Sn; ++d) {
        float sv = srow[d];
        x0 = fmaf(sv, W[d*3+0], x0);
        x1 = fmaf(sv, W[d*3+1], x1);
        x2 = fmaf(sv, W[d*3+2], x2);
      }
      const float* R8 = sR[nl]; const float* T8 = sT[nl];
      dst[0] = R8[0]*x0 + R8[1]*x1 + R8[2]*x2 + T8[0];
      dst[1] = R8[3]*x0 + R8[4]*x1 + R8[5]*x2 + T8[1];
      dst[2] = R8[6]*x0 + R8[7]*x1 + R8[8]*x2 + T8[2];
    }
  }
}

// ---------------------------------------------------------------------------
// Kernel A2: pack per-(m,h) logit operands.
// kc[m][h][0:16]=0.25*k, [16:28]=2g*lkp ; qc[m][h][0:16]=q, [16:28]=lqp
// d1[m][h] = -g*|lkp|^2 ; d0[m][h] = -g*|lqp|^2
// ---------------------------------------------------------------------------
__global__ __launch_bounds__(256) void ipa_pack(
    const float* __restrict__ scale_head, float* __restrict__ ws)
{
  const float* q   = ws + OFF_Q;
  const float* k   = ws + OFF_K;
  const float* lkp = ws + OFF_LKP;
  const float* lqp = ws + OFF_LQP;
  float* kc = ws + OFF_KC;
  float* qc = ws + OFF_QC;
  float* d1 = ws + OFF_D1;
  float* d0 = ws + OFF_D0;
  const int idx = blockIdx.x*256 + threadIdx.x;   // 0..6143
  const int h = idx >> 9, m = idx & 511;
  const float gamma = 0.11785113019775793f * log1pf(__expf(scale_head[h]));
  const float* kr  = k   + ((size_t)h*NRES + m)*En;
  const float* qr  = q   + ((size_t)h*NRES + m)*En;
  const float* lkr = lkp + ((size_t)h*NRES + m)*12;
  const float* lqr = lqp + ((size_t)h*NRES + m)*12;
  float* kcr = kc + ((size_t)m*HH + h)*28;
  float* qcr = qc + ((size_t)m*HH + h)*28;
  #pragma unroll
  for (int e = 0; e < En; ++e) { kcr[e] = 0.25f * kr[e]; qcr[e] = qr[e]; }
  float Bm = 0.f, An = 0.f;
  #pragma unroll
  for (int j = 0; j < 12; ++j) {
    float b = lkr[j], a = lqr[j];
    kcr[16+j] = (2.f*gamma)*b;
    qcr[16+j] = a;
    Bm = fmaf(b, b, Bm);
    An = fmaf(a, a, An);
  }
  d1[m*HH + h] = -gamma*Bm;
  d0[m*HH + h] = -gamma*An;
}

// ---------------------------------------------------------------------------
// Kernel B: logits[h][n][m]. Cluster reads, loads INSIDE the loop (no reg
// burst -> no spill; R10/R11 regression was launch_bounds-forced scratch
// spill at VGPR=64). Wave = 16 row-clusters x 4 lanes (r,cq): 4-lane cluster
// consumes full 64B lines of rows m and m+64. Wb in LDS (broadcast).
// Butterfly over cq; static head select; kc/qc tail; LDS-staged coalesced
// writes. grid (512 n, 4 mt), 256 thr, NO min-waves clamp.
// ---------------------------------------------------------------------------
__global__ __launch_bounds__(256) void ipa_logits(
    const float* __restrict__ pair, const float* __restrict__ Wb,
    float* __restrict__ ws)
{
  const float* kc = ws + OFF_KC;
  const float* qc = ws + OFF_QC;
  const float* d1 = ws + OFF_D1;
  const float* d0 = ws + OFF_D0;
  float* lg = ws + OFF_LG;

  __shared__ float sWb[HH*Cn];      // 6 KB
  __shared__ float sOut[HH*132];    // 6.2 KB, pad 132
  for (int i = threadIdx.x; i < HH*Cn/4; i += 256)
    reinterpret_cast<float4*>(sWb)[i] = reinterpret_cast<const float4*>(Wb)[i];
  __syncthreads();

  const int n    = blockIdx.x;
  const int tid  = threadIdx.x;
  const int lane = tid & 63;
  const int wave = tid >> 6;
  const int r    = lane >> 2;     // 0..15
  const int cq   = lane & 3;      // 0..3
  const int ml   = wave*16 + r;   // 0..63 local m
  const int m    = blockIdx.y*128 + ml;
  const int m2   = m + 64;

  const float* p1 = pair + ((size_t)n*NRES + m )*Cn + cq*4;
  const float* p2 = pair + ((size_t)n*NRES + m2)*Cn + cq*4;

  float acc1[HH], acc2[HH];
  #pragma unroll
  for (int h = 0; h < HH; ++h) { acc1[h] = 0.f; acc2[h] = 0.f; }

  #pragma unroll
  for (int jg = 0; jg < 8; ++jg) {
    float4 pv = *reinterpret_cast<const float4*>(p1 + jg*16);
    float4 pw = *reinterpret_cast<const float4*>(p2 + jg*16);
    #pragma unroll
    for (int h = 0; h < HH; ++h) {
      const float4 wb = *reinterpret_cast<const float4*>(&sWb[h*Cn + jg*16 + cq*4]);
      acc1[h] += pv.x*wb.x + pv.y*wb.y + pv.z*wb.z + pv.w*wb.w;
      acc2[h] += pw.x*wb.x + pw.y*wb.y + pw.z*wb.z + pw.w*wb.w;
    }
  }
  // butterfly over the 4 cq lanes: every lane gets full 128-ch sums
  #pragma unroll
  for (int h = 0; h < HH; ++h) {
    acc1[h] += __shfl_xor(acc1[h], 1);
    acc1[h] += __shfl_xor(acc1[h], 2);
    acc2[h] += __shfl_xor(acc2[h], 1);
    acc2[h] += __shfl_xor(acc2[h], 2);
  }
  // static 4-way select of this lane's 3 heads (no runtime-indexed regs)
  float b10, b11, b12, b20, b21, b22;
  if      (cq == 0) { b10=acc1[0]; b11=acc1[1];  b12=acc1[2];
                      b20=acc2[0]; b21=acc2[1];  b22=acc2[2]; }
  else if (cq == 1) { b10=acc1[3]; b11=acc1[4];  b12=acc1[5];
                      b20=acc2[3]; b21=acc2[4];  b22=acc2[5]; }
  else if (cq == 2) { b10=acc1[6]; b11=acc1[7];  b12=acc1[8];
                      b20=acc2[6]; b21=acc2[7];  b22=acc2[8]; }
  else              { b10=acc1[9]; b11=acc1[10]; b12=acc1[11];
                      b20=acc2[9]; b21=acc2[10]; b22=acc2[11]; }

  const int hb = 3*cq;
  const float* kc1 = kc + ((size_t)m *HH + hb)*28;
  const float* kc2 = kc + ((size_t)m2*HH + hb)*28;
  const float* qcn = qc + ((size_t)n *HH + hb)*28;
  const float* d0n = d0 + (size_t)n*HH + hb;
  const float* d11 = d1 + (size_t)m *HH + hb;
  const float* d12 = d1 + (size_t)m2*HH + hb;

  #pragma unroll
  for (int i = 0; i < 3; ++i) {
    float t1 = (i==0 ? b10 : i==1 ? b11 : b12) + d11[i] + d0n[i];
    float t2 = (i==0 ? b20 : i==1 ? b21 : b22) + d12[i] + d0n[i];
    #pragma unroll
    for (int j = 0; j < 7; ++j) {
      float4 qv = *reinterpret_cast<const float4*>(qcn + i*28 + j*4);
      float4 k1 = *reinterpret_cast<const float4*>(kc1 + i*28 + j*4);
      float4 k2 = *reinterpret_cast<const float4*>(kc2 + i*28 + j*4);
      t1 += k1.x*qv.x + k1.y*qv.y + k1.z*qv.z + k1.w*qv.w;
      t2 += k2.x*qv.x + k2.y*qv.y + k2.z*qv.z + k2.w*qv.w;
    }
    sOut[(hb+i)*132 + ml]      = t1;
    sOut[(hb+i)*132 + ml + 64] = t2;
  }
  __syncthreads();
  // coalesced full-line writes: 12 heads x 128 floats = 384 float4
  for (int idx = tid; idx < HH*32; idx += 256) {
    const int h = idx >> 5, q4 = idx & 31;
    float4 o = make_float4(sOut[h*132 + q4*4 + 0], sOut[h*132 + q4*4 + 1],
                           sOut[h*132 + q4*4 + 2], sOut[h*132 + q4*4 + 3]);
    *reinterpret_cast<float4*>(
        lg + ((size_t)h*NRES + n)*NRES + blockIdx.y*128 + q4*4) = o;
  }
}

// ---------------------------------------------------------------------------
// Kernel C: softmax in place over last axis of lg[H][N][N]. One wave per row.
// ---------------------------------------------------------------------------
__global__ __launch_bounds__(256) void ipa_softmax(float* __restrict__ ws)
{
  float* lg = ws + OFF_LG;
  const int row  = blockIdx.x*4 + (threadIdx.x >> 6);
  const int lane = threadIdx.x & 63;
  float4* p = reinterpret_cast<float4*>(lg + (size_t)row*NRES);
  float4 x0 = p[lane];
  float4 x1 = p[64 + lane];
  float mx = fmaxf(fmaxf(fmaxf(x0.x,x0.y),fmaxf(x0.z,x0.w)),
                   fmaxf(fmaxf(x1.x,x1.y),fmaxf(x1.z,x1.w)));
  #pragma unroll
  for (int off = 32; off >= 1; off >>= 1) mx = fmaxf(mx, __shfl_xor(mx, off));
  x0.x = __expf(x0.x-mx); x0.y = __expf(x0.y-mx); x0.z = __expf(x0.z-mx); x0.w = __expf(x0.w-mx);
  x1.x = __expf(x1.x-mx); x1.y = __expf(x1.y-mx); x1.z = __expf(x1.z-mx); x1.w = __expf(x1.w-mx);
  float sum = x0.x+x0.y+x0.z+x0.w + x1.x+x1.y+x1.z+x1.w;
  #pragma unroll
  for (int off = 32; off >= 1; off >>= 1) sum += __shfl_xor(sum, off);
  const float inv = 1.f/sum;
  x0.x*=inv; x0.y*=inv; x0.z*=inv; x0.w*=inv;
  x1.x*=inv; x1.y*=inv; x1.z*=inv; x1.w*=inv;
  p[lane] = x0;
  p[64 + lane] = x1;
}

// ---------------------------------------------------------------------------
// Kernel D: colsum[b][h] = sum_a w[h][a][b] (transposed). grid (12, 8).
// ---------------------------------------------------------------------------
__global__ __launch_bounds__(256) void ipa_colsum(float* __restrict__ ws)
{
  const float* lg = ws + OFF_LG;
  float* cs = ws + OFF_CS;
  const int h = blockIdx.x, ac = blockIdx.y, tid = threadIdx.x;
  const float* base = lg + (size_t)h*NRES*NRES + (size_t)ac*64*NRES;
  float acc0 = 0.f, acc1 = 0.f;
  #pragma unroll 4
  for (int a = 0; a < 64; ++a) {
    acc0 += base[(size_t)a*NRES + tid];
    acc1 += base[(size_t)a*NRES + tid + 256];
  }
  atomicAdd(&cs[(size_t)tid*HH + h],       acc0);
  atomicAdd(&cs[(size_t)(tid+256)*HH + h], acc1);
}

// ---------------------------------------------------------------------------
// Kernel E: att_single = w.v, local_out = w.lvp, inverse frame + norms.
// ---------------------------------------------------------------------------
__global__ __launch_bounds__(256) void ipa_agg(
    const float* __restrict__ Rm, const float* __restrict__ tr,
    float* __restrict__ ws)
{
  const float* v   = ws + OFF_V;
  const float* lvp = ws + OFF_LVP;
  const float* lg  = ws + OFF_LG;
  float* att = ws + OFF_ATT;
  const int row  = blockIdx.x*4 + (threadIdx.x >> 6);
  const int lane = threadIdx.x & 63;
  const int h = row >> 9, n = row & 511;

  float acc[40];
  #pragma unroll
  for (int i = 0; i < 40; ++i) acc[i] = 0.f;

  const float* wrow = lg + (size_t)row*NRES;
  #pragma unroll 2
  for (int j = 0; j < 8; ++j) {
    const int m = j*64 + lane;
    const float wv = wrow[m];
    const float4* v4 = reinterpret_cast<const float4*>(v + ((size_t)h*NRES + m)*En);
    float4 a0=v4[0], a1=v4[1], a2=v4[2], a3=v4[3];
    acc[0]+=wv*a0.x; acc[1]+=wv*a0.y; acc[2]+=wv*a0.z; acc[3]+=wv*a0.w;
    acc[4]+=wv*a1.x; acc[5]+=wv*a1.y; acc[6]+=wv*a1.z; acc[7]+=wv*a1.w;
    acc[8]+=wv*a2.x; acc[9]+=wv*a2.y; acc[10]+=wv*a2.z; acc[11]+=wv*a2.w;
    acc[12]+=wv*a3.x; acc[13]+=wv*a3.y; acc[14]+=wv*a3.z; acc[15]+=wv*a3.w;
    const float4* l4 = reinterpret_cast<const float4*>(lvp + ((size_t)h*NRES + m)*24);
    #pragma unroll
    for (int t = 0; t < 6; ++t) {
      float4 b = l4[t];
      acc[16+4*t+0]+=wv*b.x; acc[16+4*t+1]+=wv*b.y;
      acc[16+4*t+2]+=wv*b.z; acc[16+4*t+3]+=wv*b.w;
    }
  }
  #pragma unroll
  for (int off = 32; off >= 1; off >>= 1) {
    #pragma unroll
    for (int i = 0; i < 40; ++i) acc[i] += __shfl_xor(acc[i], off);
  }
  if (lane == 0) {
    size_t ab = (size_t)n*ATT_COLS;
    float4* as = reinterpret_cast<float4*>(att + ab + h*En);
    as[0] = make_float4(acc[0],acc[1],acc[2],acc[3]);
    as[1] = make_float4(acc[4],acc[5],acc[6],acc[7]);
    as[2] = make_float4(acc[8],acc[9],acc[10],acc[11]);
    as[3] = make_float4(acc[12],acc[13],acc[14],acc[15]);
    const float R0=Rm[n*9+0],R1=Rm[n*9+1],R2=Rm[n*9+2],
                R3=Rm[n*9+3],R4=Rm[n*9+4],R5=Rm[n*9+5],
                R6=Rm[n*9+6],R7=Rm[n*9+7],R8=Rm[n*9+8];
    const float t0=tr[n*3+0], t1=tr[n*3+1], t2=tr[n*3+2];
    #pragma unroll
    for (int pp = 0; pp < 8; ++pp) {
      float d0 = acc[16+3*pp+0]-t0, d1 = acc[16+3*pp+1]-t1, d2 = acc[16+3*pp+2]-t2;
      float g0 = R0*d0 + R3*d1 + R6*d2;
      float g1 = R1*d0 + R4*d1 + R7*d2;
      float g2 = R2*d0 + R5*d1 + R8*d2;
      att[ab + 1728 + (pp*HH + h)*3 + 0] = g0;
      att[ab + 1728 + (pp*HH + h)*3 + 1] = g1;
      att[ab + 1728 + (pp*HH + h)*3 + 2] = g2;
      att[ab + 2016 + pp*HH + h] = sqrtf(g0*g0 + g1*g1 + g2*g2);
    }
  }
}

// ---------------------------------------------------------------------------
// Kernel F: att_pair[h,i,c] = sum_b cs[b][h]*pair[i,b,c]. One block per i.
// 256 thr (8 b-groups x 32 c4), multi-round 24KB reduce -> 48 KB LDS total.
// ---------------------------------------------------------------------------
__global__ __launch_bounds__(256) void ipa_pairagg(
    const float* __restrict__ pair, float* __restrict__ ws)
{
  const float* cs = ws + OFF_CS;       // [b][h]
  float* att = ws + OFF_ATT;
  const int i = blockIdx.x, tid = threadIdx.x;
  __shared__ float sCS[NRES*HH];       // 24 KB
  __shared__ float4 sRed[4][HH][32];   // 24 KB
  #pragma unroll
  for (int it = 0; it < 6; ++it) {
    int idx = it*256 + tid;
    reinterpret_cast<float4*>(sCS)[idx] = reinterpret_cast<const float4*>(cs)[idx];
  }
  __syncthreads();
  const int c4 = tid & 31, bg = tid >> 5;
  const int b0 = bg * 64;
  float4 acc[HH];
  #pragma unroll
  for (int h = 0; h < HH; ++h) acc[h] = make_float4(0.f,0.f,0.f,0.f);
  const float* prow = pair + (size_t)i*NRES*Cn;
  for (int jb = 0; jb < 64; jb += 4) {
    float4 pv[4];
    #pragma unroll
    for (int u = 0; u < 4; ++u)
      pv[u] = *reinterpret_cast<const float4*>(prow + (size_t)(b0+jb+u)*Cn + c4*4);
    #pragma unroll
    for (int u = 0; u < 4; ++u) {
      const float4* csr = reinterpret_cast<const float4*>(&sCS[(b0+jb+u)*HH]);
      float4 c0 = csr[0], c1 = csr[1], c2 = csr[2];
      float w[12] = {c0.x,c0.y,c0.z,c0.w, c1.x,c1.y,c1.z,c1.w, c2.x,c2.y,c2.z,c2.w};
      #pragma unroll
      for (int h = 0; h < HH; ++h) {
        acc[h].x = fmaf(w[h], pv[u].x, acc[h].x);
        acc[h].y = fmaf(w[h], pv[u].y, acc[h].y);
        acc[h].z = fmaf(w[h], pv[u].z, acc[h].z);
        acc[h].w = fmaf(w[h], pv[u].w, acc[h].w);
      }
    }
  }
  if (bg >= 4) {
    for (int h = 0; h < HH; ++h) sRed[bg-4][h][c4] = acc[h];
  }
  __syncthreads();
  if (bg < 4) {
    for (int h = 0; h < HH; ++h) {
      float4 b2 = sRed[bg][h][c4];
      acc[h].x+=b2.x; acc[h].y+=b2.y; acc[h].z+=b2.z; acc[h].w+=b2.w;
    }
  }
  __syncthreads();
  if (bg >= 2 && bg < 4) {
    for (int h = 0; h < HH; ++h) sRed[bg-2][h][c4] = acc[h];
  }
  __syncthreads();
  if (bg < 2) {
    for (int h = 0; h < HH; ++h) {
      float4 b2 = sRed[bg][h][c4];
      acc[h].x+=b2.x; acc[h].y+=b2.y; acc[h].z+=b2.z; acc[h].w+=b2.w;
    }
  }
  __syncthreads();
  if (bg == 1) {
    for (int h = 0; h < HH; ++h) sRed[0][h][c4] = acc[h];
  }
  __syncthreads();
  if (bg == 0) {
    size_t base = (size_t)i*ATT_COLS + 192;
    for (int h = 0; h < HH; ++h) {
      float4 b2 = sRed[0][h][c4];
      acc[h].x+=b2.x; acc[h].y+=b2.y; acc[h].z+=b2.z; acc[h].w+=b2.w;
      *reinterpret_cast<float4*>(att + base + h*Cn + c4*4) = acc[h];
    }
  }
}

// ---------------------------------------------------------------------------
// Kernel G1: split-k partial GEMM. grid (64 rowblocks, 16 ksplits), 384 thr.
// ---------------------------------------------------------------------------
__global__ __launch_bounds__(384) void ipa_outp(
    const float* __restrict__ att, const float* __restrict__ Wout,
    float* __restrict__ ws)
{
  float* partial = ws + OFF_PART;       // [KSPLIT][NRES][Sn]
  const int rb = blockIdx.x;
  const int ks = blockIdx.y;
  const int s  = threadIdx.x;
  const int n0 = rb*OROWS;
  const int j0 = ks*KCHUNK;

  float acc[OROWS];
  #pragma unroll
  for (int r = 0; r < OROWS; ++r) acc[r] = 0.f;

  for (int jg = 0; jg < KCHUNK/4; ++jg) {
    const int j = j0 + jg*4;
    float w0 = Wout[(size_t)(j+0)*Sn + s];
    float w1 = Wout[(size_t)(j+1)*Sn + s];
    float w2 = Wout[(size_t)(j+2)*Sn + s];
    float w3 = Wout[(size_t)(j+3)*Sn + s];
    #pragma unroll
    for (int r = 0; r < OROWS; ++r) {
      float4 av = *reinterpret_cast<const float4*>(att + (size_t)(n0+r)*ATT_COLS + j);
      acc[r] = fmaf(av.x, w0, acc[r]);
      acc[r] = fmaf(av.y, w1, acc[r]);
      acc[r] = fmaf(av.z, w2, acc[r]);
      acc[r] = fmaf(av.w, w3, acc[r]);
    }
  }
  #pragma unroll
  for (int r = 0; r < OROWS; ++r)
    partial[((size_t)ks*NRES + n0 + r)*Sn + s] = acc[r];
}

// ---------------------------------------------------------------------------
// Kernel G2: out[n][s] = b_out[s] + sum_ks partial[ks][n][s].
// ---------------------------------------------------------------------------
__global__ __launch_bounds__(384) void ipa_outred(
    const float* __restrict__ b_out, float* __restrict__ ws,
    float* __restrict__ out)
{
  const float* partial = ws + OFF_PART;
  const int n = blockIdx.x, s = threadIdx.x;
  float a = b_out[s];
  #pragma unroll
  for (int ks = 0; ks < KSPLIT; ++ks)
    a += partial[((size_t)ks*NRES + n)*Sn + s];
  out[(size_t)n*Sn + s] = a;
}

// ---------------------------------------------------------------------------
extern "C" void kernel_launch(void* const* d_in, const int* in_sizes, int n_in,
                              void* d_out, int out_size, void* d_ws, size_t ws_size,
                              hipStream_t stream) {
  const float* single = (const float*)d_in[0];
  const float* pair   = (const float*)d_in[1];
  const float* Rm     = (const float*)d_in[2];
  const float* tr     = (const float*)d_in[3];
  const float* Wq     = (const float*)d_in[4];
  const float* Wk     = (const float*)d_in[5];
  const float* Wv     = (const float*)d_in[6];
  const float* Wqp    = (const float*)d_in[7];
  const float* Wkp    = (const float*)d_in[8];
  const float* Wvp    = (const float*)d_in[9];
  const float* Wb     = (const float*)d_in[10];
  const float* Wout   = (const float*)d_in[11];
  const float* b_out  = (const float*)d_in[12];
  const float* scale_head = (const float*)d_in[13];
  float* ws  = (float*)d_ws;
  float* out = (float*)d_out;

  hipMemsetAsync(ws + OFF_CS, 0, NRES*HH*sizeof(float), stream);
  ipa_proj   <<<dim3(64, 8),  256, 0, stream>>>(single, Rm, tr, Wq, Wk, Wv, Wqp, Wkp, Wvp, ws);
  ipa_pack   <<<dim3(24),     256, 0, stream>>>(scale_head, ws);
  ipa_logits <<<dim3(NRES, 4), 256, 0, stream>>>(pair, Wb, ws);
  ipa_softmax<<<dim3(HH*NRES/4), 256, 0, stream>>>(ws);
  ipa_colsum <<<dim3(HH, 8),  256, 0, stream>>>(ws);
  ipa_agg    <<<dim3(HH*NRES/4), 256, 0, stream>>>(Rm, tr, ws);
  ipa_pairagg<<<dim3(NRES),   256, 0, stream>>>(pair, ws);
  ipa_outp   <<<dim3(NRES/OROWS, KSPLIT), 384, 0, stream>>>(ws + OFF_ATT, Wout, ws);
  ipa_outred <<<dim3(NRES),   384, 0, stream>>>(b_out, ws, out);
}